// Round 4
// baseline (255.087 us; speedup 1.0000x reference)
//
#include <hip/hip_runtime.h>
#include <math.h>

#define NSLOT 256
#define HWN   16384
#define D_    256
#define BB    4
#define NSEL  768
#define NPOS  512
#define NHEAD 8
#define AFFP  772
#define WEXP  516

// ---------------- Kernel A: per-slot top-768 stable select (1024 thr) ----------------
__global__ __launch_bounds__(1024) void topk_kernel(const float* __restrict__ curio,
                                                    int* __restrict__ feat_sel) {
  __shared__ unsigned int hist[4096];
  __shared__ unsigned int wsum[16];
  __shared__ unsigned long long skey[2048];
  __shared__ int sBstar;
  __shared__ unsigned int sCount;
  int s = blockIdx.x;
  int t = threadIdx.x;
  int wave = t >> 6, lane = t & 63;
  const float* row = curio + (size_t)s * HWN;

  for (int i = t; i < 4096; i += 1024) hist[i] = 0;
  if (t == 0) sCount = 0;
  __syncthreads();
  for (int j = t; j < HWN; j += 1024) {
    unsigned int bits = __float_as_uint(row[j]);   // values in [0,1): bits monotone
    atomicAdd(&hist[bits >> 18], 1u);
  }
  __syncthreads();
  unsigned int cs = hist[t * 4] + hist[t * 4 + 1] + hist[t * 4 + 2] + hist[t * 4 + 3];
  unsigned int v = cs;
#pragma unroll
  for (int off = 1; off < 64; off <<= 1) {
    unsigned int u = __shfl_down(v, off, 64);
    if (lane + off < 64) v += u;       // suffix over lanes >= lane (this wave)
  }
  if (lane == 0) wsum[wave] = v;
  __syncthreads();
  unsigned int above = 0;
  for (int w2 = wave + 1; w2 < 16; w2++) above += wsum[w2];
  unsigned int sufAfter = above + (v - cs);
  if (sufAfter < NSEL && sufAfter + cs >= NSEL) {
    unsigned int local = sufAfter;
    for (int b = t * 4 + 3; b >= t * 4; b--) {
      unsigned int c = hist[b];
      if (local + c >= NSEL) { sBstar = b; break; }
      local += c;
    }
  }
  __syncthreads();
  int bstar = sBstar;
  for (int j = t; j < HWN; j += 1024) {
    unsigned int bits = __float_as_uint(row[j]);
    if ((int)(bits >> 18) >= bstar) {
      unsigned int pos = atomicAdd(&sCount, 1u);
      if (pos < 2048)
        skey[pos] = ((unsigned long long)bits << 14) | (unsigned long long)(16383 - j);
    }
  }
  __syncthreads();
  unsigned int M = sCount;
  int SZ = (M <= 1024) ? 1024 : 2048;
  for (int i = t; i < SZ; i += 1024) if (i >= (int)M) skey[i] = 0ull;
  for (int k = 2; k <= SZ; k <<= 1) {
    for (int j2 = k >> 1; j2 > 0; j2 >>= 1) {
      __syncthreads();
      for (int i = t; i < SZ; i += 1024) {
        int l = i ^ j2;
        if (l > i) {
          unsigned long long a = skey[i], b = skey[l];
          bool dir = ((i & k) == 0);
          if ((a < b) == dir) { skey[i] = b; skey[l] = a; }
        }
      }
    }
  }
  __syncthreads();
  for (int r = t; r < NSEL; r += 1024)
    feat_sel[s * NSEL + r] = 16383 - (int)(skey[r] & 16383ull);
}

// ---------------- Mega kernel ----------------
__global__ __launch_bounds__(1024) void mega_kernel(
    const float* __restrict__ slots, const float* __restrict__ features,
    const float* __restrict__ posenc, const int* __restrict__ batch_idx,
    const int* __restrict__ feat_sel,
    const float* __restrict__ ipw, const float* __restrict__ ipb,
    const float* __restrict__ wout, const float* __restrict__ bout,
    const float* __restrict__ lnw, const float* __restrict__ lnb,
    float* __restrict__ slots_new, float* __restrict__ norm_aff) {
  __shared__ float aff[NHEAD][AFFP];     // 24.7 KB  (conflict-free pass-A writes)
  __shared__ float wexpT[NHEAD][WEXP];   // 16.5 KB  (exp'd weights, broadcast reads)
  __shared__ float qks[NHEAD][D_];       // 8 KB
  __shared__ float fbar[NHEAD][D_];      // 8 KB
  __shared__ float aff2s[NSEL];          // 3 KB
  __shared__ int   sfsel[NSEL];          // 3 KB
  __shared__ float srow[D_];
  __shared__ float qrow[D_];
  __shared__ float pq[1024];
  __shared__ float outv[D_];
  __shared__ float qbk_s[NHEAD], sinv[NHEAD];
  __shared__ float redS[16], redQ[16];

  int s = blockIdx.x, t = threadIdx.x;
  int wave = t >> 6, lane = t & 63;
  int bi = batch_idx[s];
  const int* fsel = feat_sel + s * NSEL;

  // P0: stage slot row, fsel; zero fbar
  if (t < 64) ((float4*)srow)[t] = ((const float4*)(slots + (size_t)s * D_))[t];
  if (t < NSEL) sfsel[t] = fsel[t];
  for (int i = t; i < NHEAD * D_; i += 1024) ((float*)fbar)[i] = 0.f;
  __syncthreads();

  // P1: q = (Wq . srow + bq) * scaling   (quarter-dots)
  {
    int o = t >> 2, part = t & 3;
    const float4* w4 = (const float4*)(ipw + (size_t)o * D_ + part * 64);
    float a = 0.f;
#pragma unroll
    for (int i = 0; i < 16; i++) {
      float4 w = w4[i];
      int d = part * 64 + i * 4;
      a += srow[d] * w.x + srow[d + 1] * w.y + srow[d + 2] * w.z + srow[d + 3] * w.w;
    }
    pq[t] = a;
  }
  __syncthreads();
  if (t < D_)
    qrow[t] = (pq[t * 4] + pq[t * 4 + 1] + pq[t * 4 + 2] + pq[t * 4 + 3] + ipb[t]) *
              0.17677669529663689f;  // 1/sqrt(32)
  __syncthreads();

  // P2: qk[h][c] = sum_e qrow[h*32+e] * Wk[h*32+e][c]
  if (t < 512) {
    int h = t >> 6, c4 = t & 63;
    float4 a = {0.f, 0.f, 0.f, 0.f};
    const float4* wk = (const float4*)ipw + (size_t)(D_ + h * 32) * 64 + c4;
#pragma unroll
    for (int e = 0; e < 32; e++) {
      float q = qrow[h * 32 + e];
      float4 w = wk[(size_t)e * 64];
      a.x += q * w.x; a.y += q * w.y; a.z += q * w.z; a.w += q * w.w;
    }
    ((float4*)qks[h])[c4] = a;
  } else if (t < 520) {
    int h = t - 512;
    float a = 0.f;
    for (int e = 0; e < 32; e++) a += qrow[h * 32 + e] * ipb[D_ + h * 32 + e];
    qbk_s[h] = a;
  }
  __syncthreads();

  // ---- Pass A: aff for all 768 rows. 16 lanes per row, 4 rows per wave-tile.
  // Zero cross-lane ops in the hot loop; finish = 3 value-split shuffles + 1 plain.
  {
    int q16 = lane & 15;         // position within row-group
    int rg = lane >> 4;          // row within tile (0..3)
    int hmine = ((q16 >> 3) & 1) * 4 + ((q16 >> 2) & 1) * 2 + ((q16 >> 1) & 1);
    float qbk_mine = qbk_s[hmine];
    for (int tile = wave; tile < NSEL / 4; tile += 16) {
      int n = tile * 4 + rg;
      int idx = sfsel[n];
      size_t rowbase = ((size_t)idx * BB + bi) * D_ + (size_t)(q16 * 4);
      float4 kf[4];
#pragma unroll
      for (int i = 0; i < 4; i++) {
        const float4 f4 = *(const float4*)(features + rowbase + i * 64);
        const float4 p4 = *(const float4*)(posenc + rowbase + i * 64);
        kf[i].x = f4.x + p4.x; kf[i].y = f4.y + p4.y;
        kf[i].z = f4.z + p4.z; kf[i].w = f4.w + p4.w;
      }
      float p[NHEAD];
#pragma unroll
      for (int h = 0; h < NHEAD; h++) p[h] = 0.f;
#pragma unroll
      for (int i = 0; i < 4; i++) {
#pragma unroll
        for (int h = 0; h < NHEAD; h++) {
          const float4 w = *(const float4*)&qks[h][i * 64 + q16 * 4];
          p[h] += kf[i].x * w.x + kf[i].y * w.y + kf[i].z * w.z + kf[i].w * w.w;
        }
      }
      // finish across 16 lanes: splits over xor 8,4,2 then plain xor 1
      float v[4];
#pragma unroll
      for (int j = 0; j < 4; j++) {
        float keep = (lane & 8) ? p[j + 4] : p[j];
        float send = (lane & 8) ? p[j] : p[j + 4];
        v[j] = keep + __shfl_xor(send, 8, 64);
      }
      float w2[2];
#pragma unroll
      for (int j = 0; j < 2; j++) {
        float keep = (lane & 4) ? v[j + 2] : v[j];
        float send = (lane & 4) ? v[j] : v[j + 2];
        w2[j] = keep + __shfl_xor(send, 4, 64);
      }
      float r;
      {
        float keep = (lane & 2) ? w2[1] : w2[0];
        float send = (lane & 2) ? w2[0] : w2[1];
        r = keep + __shfl_xor(send, 2, 64);
      }
      r += __shfl_xor(r, 1, 64);
      if (!(lane & 1)) aff[hmine][n] = r + qbk_mine;   // 32 writes, banks 4h+rg: conflict-free
    }
  }
  __syncthreads();

  // P4: exp+denominator (waves 0-7; exp ONCE per (h,n); no max needed: |aff|<~30)
  //     || aff2 mean + LN stats (waves 8-15)
  if (wave < NHEAD) {
    int h = wave;
    float sum = 0.f;
    for (int n = lane; n < NPOS; n += 64) {
      float e = __expf(aff[h][n]);
      wexpT[h][n] = e;
      sum += e;
    }
#pragma unroll
    for (int off = 32; off >= 1; off >>= 1) sum += __shfl_xor(sum, off, 64);
    if (lane == 0) sinv[h] = 1.0f / sum;
  } else {
    int idx = t - 512;  // 0..511
    float ls = 0.f, lq = 0.f;
    {
      float a = 0.f;
#pragma unroll
      for (int h = 0; h < NHEAD; h++) a += aff[h][idx];
      a *= (1.0f / NHEAD);
      aff2s[idx] = a;
      ls += a; lq += a * a;
    }
    if (idx < NSEL - NPOS) {
      int n = idx + NPOS;
      float a = 0.f;
#pragma unroll
      for (int h = 0; h < NHEAD; h++) a += aff[h][n];
      a *= (1.0f / NHEAD);
      aff2s[n] = a;
      ls += a; lq += a * a;
    }
#pragma unroll
    for (int off = 32; off >= 1; off >>= 1) { ls += __shfl_xor(ls, off, 64); lq += __shfl_xor(lq, off, 64); }
    if (lane == 0) { redS[wave] = ls; redQ[wave] = lq; }
  }
  __syncthreads();

  // P5: norm_aff write
  {
    float tots = 0.f, totq = 0.f;
#pragma unroll
    for (int w2 = 8; w2 < 16; w2++) { tots += redS[w2]; totq += redQ[w2]; }
    float mean = tots * (1.0f / NSEL);
    float var = totq * (1.0f / NSEL) - mean * mean;
    float rstd = rsqrtf(var + 1e-5f);
    if (t < NSEL) norm_aff[(size_t)t * NSLOT + s] = (aff2s[t] - mean) * rstd;
  }

  // ---- Pass B: PV. Wave-per-row coalesced f re-gather, weights broadcast from LDS.
  {
    float acc[NHEAD][4];
#pragma unroll
    for (int h = 0; h < NHEAD; h++)
#pragma unroll
      for (int j = 0; j < 4; j++) acc[h][j] = 0.f;
    for (int nn = wave; nn < NPOS; nn += 32) {
      int nA = nn, nB = nn + 16;
      int idxA = sfsel[nA], idxB = sfsel[nB];
      size_t baseA = ((size_t)idxA * BB + bi) * D_ + (size_t)(lane * 4);
      size_t baseB = ((size_t)idxB * BB + bi) * D_ + (size_t)(lane * 4);
      const float4 fA = *(const float4*)(features + baseA);
      const float4 fB = *(const float4*)(features + baseB);
      float wA[NHEAD], wB[NHEAD];
#pragma unroll
      for (int h = 0; h < NHEAD; h++) { wA[h] = wexpT[h][nA]; wB[h] = wexpT[h][nB]; }
#pragma unroll
      for (int h = 0; h < NHEAD; h++) {
        acc[h][0] += wA[h] * fA.x; acc[h][1] += wA[h] * fA.y;
        acc[h][2] += wA[h] * fA.z; acc[h][3] += wA[h] * fA.w;
      }
#pragma unroll
      for (int h = 0; h < NHEAD; h++) {
        acc[h][0] += wB[h] * fB.x; acc[h][1] += wB[h] * fB.y;
        acc[h][2] += wB[h] * fB.z; acc[h][3] += wB[h] * fB.w;
      }
    }
#pragma unroll
    for (int hh = 0; hh < NHEAD; hh++) {
      int h = (hh + wave) & 7;  // stagger
      atomicAdd(&fbar[h][lane * 4 + 0], acc[h][0]);
      atomicAdd(&fbar[h][lane * 4 + 1], acc[h][1]);
      atomicAdd(&fbar[h][lane * 4 + 2], acc[h][2]);
      atomicAdd(&fbar[h][lane * 4 + 3], acc[h][3]);
    }
  }
  __syncthreads();

  // P6: out = sinv[h]*(Wv . fbar[h]) + bv   (quarter-dots)
  {
    int o = t >> 2, part = t & 3, h = o >> 5;
    const float4* wv = (const float4*)(ipw + (size_t)(2 * D_ + o) * D_ + part * 64);
    float a = 0.f;
#pragma unroll
    for (int i = 0; i < 16; i++) {
      float4 w = wv[i];
      int d = part * 64 + i * 4;
      a += fbar[h][d] * w.x + fbar[h][d + 1] * w.y + fbar[h][d + 2] * w.z + fbar[h][d + 3] * w.w;
    }
    pq[t] = a;
  }
  __syncthreads();
  if (t < D_)
    outv[t] = (pq[t * 4] + pq[t * 4 + 1] + pq[t * 4 + 2] + pq[t * 4 + 3]) * sinv[t >> 5] +
              ipb[2 * D_ + t];
  __syncthreads();

  // P7: slots_new = LN(srow + Wout.outv + bout) * lnw + lnb
  {
    int o = t >> 2, part = t & 3;
    const float4* w4 = (const float4*)(wout + (size_t)o * D_ + part * 64);
    float a = 0.f;
#pragma unroll
    for (int i = 0; i < 16; i++) {
      float4 w = w4[i];
      int d = part * 64 + i * 4;
      a += outv[d] * w.x + outv[d + 1] * w.y + outv[d + 2] * w.z + outv[d + 3] * w.w;
    }
    pq[t] = a;
  }
  __syncthreads();
  float v = 0.f;
  if (t < D_) {
    v = srow[t] + pq[t * 4] + pq[t * 4 + 1] + pq[t * 4 + 2] + pq[t * 4 + 3] + bout[t];
    float ls = v, lq = v * v;
#pragma unroll
    for (int off = 32; off >= 1; off >>= 1) { ls += __shfl_xor(ls, off, 64); lq += __shfl_xor(lq, off, 64); }
    if (lane == 0) { redS[wave] = ls; redQ[wave] = lq; }
  }
  __syncthreads();
  if (t < D_) {
    float tots = redS[0] + redS[1] + redS[2] + redS[3];
    float totq = redQ[0] + redQ[1] + redQ[2] + redQ[3];
    float mean = tots * (1.0f / D_);
    float var = totq * (1.0f / D_) - mean * mean;
    float rstd = rsqrtf(var + 1e-5f);
    slots_new[s * D_ + t] = (v - mean) * rstd * lnw[t] + lnb[t];
  }
}

extern "C" void kernel_launch(void* const* d_in, const int* in_sizes, int n_in,
                              void* d_out, int out_size, void* d_ws, size_t ws_size,
                              hipStream_t stream) {
  const float* slots    = (const float*)d_in[0];
  const float* features = (const float*)d_in[1];
  const float* posenc   = (const float*)d_in[2];
  const float* curio    = (const float*)d_in[3];
  const int*   batch_idx= (const int*)d_in[4];
  const float* ipw      = (const float*)d_in[5];
  const float* ipb      = (const float*)d_in[6];
  const float* wout     = (const float*)d_in[7];
  const float* bout     = (const float*)d_in[8];
  const float* lnw      = (const float*)d_in[9];
  const float* lnb      = (const float*)d_in[10];

  int* feat_sel = (int*)d_ws;                 // 256*768*4 = 786432 B
  float* out_f  = (float*)d_out;              // [0,65536) slots_new, [65536,262144) norm_aff

  topk_kernel<<<NSLOT, 1024, 0, stream>>>(curio, feat_sel);
  mega_kernel<<<NSLOT, 1024, 0, stream>>>(slots, features, posenc, batch_idx, feat_sel,
                                          ipw, ipb, wout, bout, lnw, lnb,
                                          out_f, out_f + 65536);
}

// Round 6
// 189.368 us; speedup vs baseline: 1.3470x; 1.3470x over previous
//
#include <hip/hip_runtime.h>
#include <math.h>

#define NSLOT 256
#define HWN   16384
#define D_    256
#define BB    4
#define NSEL  768
#define NPOS  512
#define NHEAD 8

// Reduce 8 per-lane values over all 64 lanes simultaneously.
// Returns: full 64-lane sum of p[h], where h = (lane>>3)&7 for this lane.
__device__ __forceinline__ float reduce8x64(const float p[8], int lane) {
  float v[4];
#pragma unroll
  for (int h = 0; h < 4; h++) {
    float keep = (lane & 32) ? p[h + 4] : p[h];
    float send = (lane & 32) ? p[h] : p[h + 4];
    v[h] = keep + __shfl_xor(send, 32, 64);
  }
  float w[2];
#pragma unroll
  for (int h = 0; h < 2; h++) {
    float keep = (lane & 16) ? v[h + 2] : v[h];
    float send = (lane & 16) ? v[h] : v[h + 2];
    w[h] = keep + __shfl_xor(send, 16, 64);
  }
  float r;
  {
    float keep = (lane & 8) ? w[1] : w[0];
    float send = (lane & 8) ? w[0] : w[1];
    r = keep + __shfl_xor(send, 8, 64);
  }
  r += __shfl_xor(r, 4, 64);
  r += __shfl_xor(r, 2, 64);
  r += __shfl_xor(r, 1, 64);
  return r;
}

// ---------------- Kernel A: per-slot top-768 stable select (1024 thr) ----------------
__global__ __launch_bounds__(1024) void topk_kernel(const float* __restrict__ curio,
                                                    int* __restrict__ feat_sel) {
  __shared__ unsigned int hist[4096];
  __shared__ unsigned int wsum[16];
  __shared__ unsigned long long skey[2048];
  __shared__ int sBstar;
  __shared__ unsigned int sCount;
  int s = blockIdx.x;
  int t = threadIdx.x;
  int wave = t >> 6, lane = t & 63;
  const float* row = curio + (size_t)s * HWN;

  for (int i = t; i < 4096; i += 1024) hist[i] = 0;
  if (t == 0) sCount = 0;
  __syncthreads();
  for (int j = t; j < HWN; j += 1024) {
    unsigned int bits = __float_as_uint(row[j]);   // values in [0,1): bits monotone
    atomicAdd(&hist[bits >> 18], 1u);
  }
  __syncthreads();
  unsigned int cs = hist[t * 4] + hist[t * 4 + 1] + hist[t * 4 + 2] + hist[t * 4 + 3];
  unsigned int v = cs;
#pragma unroll
  for (int off = 1; off < 64; off <<= 1) {
    unsigned int u = __shfl_down(v, off, 64);
    if (lane + off < 64) v += u;       // suffix over lanes >= lane (this wave)
  }
  if (lane == 0) wsum[wave] = v;
  __syncthreads();
  unsigned int above = 0;
  for (int w2 = wave + 1; w2 < 16; w2++) above += wsum[w2];
  unsigned int sufAfter = above + (v - cs);
  if (sufAfter < NSEL && sufAfter + cs >= NSEL) {
    unsigned int local = sufAfter;
    for (int b = t * 4 + 3; b >= t * 4; b--) {
      unsigned int c = hist[b];
      if (local + c >= NSEL) { sBstar = b; break; }
      local += c;
    }
  }
  __syncthreads();
  int bstar = sBstar;
  for (int j = t; j < HWN; j += 1024) {
    unsigned int bits = __float_as_uint(row[j]);
    if ((int)(bits >> 18) >= bstar) {
      unsigned int pos = atomicAdd(&sCount, 1u);
      if (pos < 2048)
        skey[pos] = ((unsigned long long)bits << 14) | (unsigned long long)(16383 - j);
    }
  }
  __syncthreads();
  unsigned int M = sCount;
  int SZ = (M <= 1024) ? 1024 : 2048;
  for (int i = t; i < SZ; i += 1024) if (i >= (int)M) skey[i] = 0ull;
  for (int k = 2; k <= SZ; k <<= 1) {
    for (int j2 = k >> 1; j2 > 0; j2 >>= 1) {
      __syncthreads();
      for (int i = t; i < SZ; i += 1024) {
        int l = i ^ j2;
        if (l > i) {
          unsigned long long a = skey[i], b = skey[l];
          bool dir = ((i & k) == 0);
          if ((a < b) == dir) { skey[i] = b; skey[l] = a; }
        }
      }
    }
  }
  __syncthreads();
  for (int r = t; r < NSEL; r += 1024)
    feat_sel[s * NSEL + r] = 16383 - (int)(skey[r] & 16383ull);
}

// ---------------- Kernel B: q projection + qk = Wk^T q (per slot, 256 thr) ----------------
__global__ __launch_bounds__(256) void qproj_kernel(const float* __restrict__ slots,
                                                    const float* __restrict__ ipw,
                                                    const float* __restrict__ ipb,
                                                    float* __restrict__ qk_g,
                                                    float* __restrict__ qbk_g) {
  __shared__ float srow[D_];
  __shared__ float qrow[D_];
  int s = blockIdx.x, t = threadIdx.x;
  srow[t] = slots[s * D_ + t];
  __syncthreads();
  {
    const float* wq = ipw + (size_t)t * D_;
    float acc = ipb[t];
    for (int d = 0; d < D_; d++) acc += srow[d] * wq[d];
    qrow[t] = acc * 0.17677669529663689f;  // 1/sqrt(32)
  }
  __syncthreads();
  for (int h = 0; h < NHEAD; h++) {
    const float* wkbase = ipw + (size_t)(D_ + h * 32) * D_ + t;
    float a = 0.f;
    for (int e = 0; e < 32; e++) a += qrow[h * 32 + e] * wkbase[(size_t)e * D_];
    qk_g[((size_t)s * NHEAD + h) * D_ + t] = a;
  }
  if (t < NHEAD) {
    float a = 0.f;
    for (int e = 0; e < 32; e++) a += qrow[t * 32 + e] * ipb[D_ + t * 32 + e];
    qbk_g[s * NHEAD + t] = a;
  }
}

// ---------------- Kernel C: aff + fused PV partials. grid = (slot, half), 512 thr ----------------
// Block (s, half) handles rows n == half (mod 2): 384 rows (256 pos, 128 neg).
// Wave w, iter i -> group g = w + 8*i (g<64: pos, else neg), rows g*4+j (j=0..3).
__global__ __launch_bounds__(512, 4) void aff_pv_kernel(
    const float* __restrict__ features, const float* __restrict__ posenc,
    const int* __restrict__ batch_idx, const int* __restrict__ feat_sel,
    const float* __restrict__ qk_g, const float* __restrict__ qbk_g,
    float* __restrict__ fbar_part,    // [256][2][8][256]
    float* __restrict__ expsum_part,  // [256][2][8]
    float* __restrict__ stat_part,    // [256][2][2]
    float* __restrict__ aff2_g) {     // [256][768]
  __shared__ float qks[NHEAD][D_];    // 8 KB
  __shared__ float fbar[NHEAD][D_];   // 8 KB
  __shared__ float wtile[8][4][8];    // 1 KB
  __shared__ int   sfsel[384];
  __shared__ float esums[8][NHEAD];
  __shared__ float sstat[8][2];
  __shared__ float qbkmean_s;

  int b = blockIdx.x, s = b >> 1, half = b & 1;
  int t = threadIdx.x, w = t >> 6, lane = t & 63;
  int bi = batch_idx[s];

  for (int i = t; i < NHEAD * D_; i += 512) {
    ((float*)qks)[i] = qk_g[(size_t)s * (NHEAD * D_) + i];
    ((float*)fbar)[i] = 0.f;
  }
  if (t < 384) sfsel[t] = feat_sel[s * NSEL + half + 2 * t];
  if (t == 0) {
    float m = 0.f;
    for (int h = 0; h < NHEAD; h++) m += qbk_g[s * NHEAD + h];
    qbkmean_s = m * 0.125f;
  }
  __syncthreads();
  float qbkmean = qbkmean_s;

  float acc[NHEAD][4];
#pragma unroll
  for (int h = 0; h < NHEAD; h++)
#pragma unroll
    for (int c = 0; c < 4; c++) acc[h][c] = 0.f;
  float esum = 0.f;              // valid on lanes with (lane&7)==0; head = lane>>3
  float st_s = 0.f, st_q = 0.f;  // valid on lane 0

  // ---- pos groups (i = 0..7): aff + PV
  for (int i = 0; i < 8; i++) {
    int g = w + 8 * i;
    float4 f4[4], k4[4];
#pragma unroll
    for (int j = 0; j < 4; j++) {
      int idx = sfsel[g * 4 + j];
      size_t base = ((size_t)idx * BB + bi) * D_ + (size_t)(lane * 4);
      f4[j] = *(const float4*)(features + base);
      const float4 p4 = *(const float4*)(posenc + base);
      k4[j].x = f4[j].x + p4.x; k4[j].y = f4[j].y + p4.y;
      k4[j].z = f4[j].z + p4.z; k4[j].w = f4[j].w + p4.w;
    }
    float pp[4][NHEAD];
#pragma unroll
    for (int h = 0; h < NHEAD; h++) {
      const float4 qw = *(const float4*)&qks[h][lane * 4];
#pragma unroll
      for (int j = 0; j < 4; j++)
        pp[j][h] = k4[j].x * qw.x + k4[j].y * qw.y + k4[j].z * qw.z + k4[j].w * qw.w;
    }
#pragma unroll
    for (int j = 0; j < 4; j++) {
      float r = reduce8x64(pp[j], lane);
      float e = __expf(r);
      if ((lane & 7) == 0) {
        wtile[w][j][lane >> 3] = e;
        esum += e;
      }
      float tsum = r;
      tsum += __shfl_xor(tsum, 8, 64);
      tsum += __shfl_xor(tsum, 16, 64);
      tsum += __shfl_xor(tsum, 32, 64);
      if (lane == 0) {
        float a2 = tsum * 0.125f + qbkmean;
        aff2_g[s * NSEL + half + 2 * (g * 4 + j)] = a2;
        st_s += a2; st_q += a2 * a2;
      }
    }
    // PV: weights broadcast from wtile (same-wave LDS, no barrier needed)
#pragma unroll
    for (int j = 0; j < 4; j++) {
      const float4 w0 = *(const float4*)&wtile[w][j][0];
      const float4 w1 = *(const float4*)&wtile[w][j][4];
      acc[0][0] += w0.x * f4[j].x; acc[0][1] += w0.x * f4[j].y; acc[0][2] += w0.x * f4[j].z; acc[0][3] += w0.x * f4[j].w;
      acc[1][0] += w0.y * f4[j].x; acc[1][1] += w0.y * f4[j].y; acc[1][2] += w0.y * f4[j].z; acc[1][3] += w0.y * f4[j].w;
      acc[2][0] += w0.z * f4[j].x; acc[2][1] += w0.z * f4[j].y; acc[2][2] += w0.z * f4[j].z; acc[2][3] += w0.z * f4[j].w;
      acc[3][0] += w0.w * f4[j].x; acc[3][1] += w0.w * f4[j].y; acc[3][2] += w0.w * f4[j].z; acc[3][3] += w0.w * f4[j].w;
      acc[4][0] += w1.x * f4[j].x; acc[4][1] += w1.x * f4[j].y; acc[4][2] += w1.x * f4[j].z; acc[4][3] += w1.x * f4[j].w;
      acc[5][0] += w1.y * f4[j].x; acc[5][1] += w1.y * f4[j].y; acc[5][2] += w1.y * f4[j].z; acc[5][3] += w1.y * f4[j].w;
      acc[6][0] += w1.z * f4[j].x; acc[6][1] += w1.z * f4[j].y; acc[6][2] += w1.z * f4[j].z; acc[6][3] += w1.z * f4[j].w;
      acc[7][0] += w1.w * f4[j].x; acc[7][1] += w1.w * f4[j].y; acc[7][2] += w1.w * f4[j].z; acc[7][3] += w1.w * f4[j].w;
    }
  }

  // ---- neg groups (i = 8..11): aff only
  for (int i = 8; i < 12; i++) {
    int g = w + 8 * i;
    float4 k4[4];
#pragma unroll
    for (int j = 0; j < 4; j++) {
      int idx = sfsel[g * 4 + j];
      size_t base = ((size_t)idx * BB + bi) * D_ + (size_t)(lane * 4);
      const float4 f4v = *(const float4*)(features + base);
      const float4 p4 = *(const float4*)(posenc + base);
      k4[j].x = f4v.x + p4.x; k4[j].y = f4v.y + p4.y;
      k4[j].z = f4v.z + p4.z; k4[j].w = f4v.w + p4.w;
    }
    float pp[4][NHEAD];
#pragma unroll
    for (int h = 0; h < NHEAD; h++) {
      const float4 qw = *(const float4*)&qks[h][lane * 4];
#pragma unroll
      for (int j = 0; j < 4; j++)
        pp[j][h] = k4[j].x * qw.x + k4[j].y * qw.y + k4[j].z * qw.z + k4[j].w * qw.w;
    }
#pragma unroll
    for (int j = 0; j < 4; j++) {
      float r = reduce8x64(pp[j], lane);
      float tsum = r;
      tsum += __shfl_xor(tsum, 8, 64);
      tsum += __shfl_xor(tsum, 16, 64);
      tsum += __shfl_xor(tsum, 32, 64);
      if (lane == 0) {
        float a2 = tsum * 0.125f + qbkmean;
        aff2_g[s * NSEL + half + 2 * (g * 4 + j)] = a2;
        st_s += a2; st_q += a2 * a2;
      }
    }
  }

  // ---- combine partials
  if ((lane & 7) == 0) esums[w][lane >> 3] = esum;
  if (lane == 0) { sstat[w][0] = st_s; sstat[w][1] = st_q; }
#pragma unroll
  for (int hh = 0; hh < NHEAD; hh++) {
    int h = (hh + w) & 7;  // stagger
    atomicAdd(&fbar[h][lane * 4 + 0], acc[h][0]);
    atomicAdd(&fbar[h][lane * 4 + 1], acc[h][1]);
    atomicAdd(&fbar[h][lane * 4 + 2], acc[h][2]);
    atomicAdd(&fbar[h][lane * 4 + 3], acc[h][3]);
  }
  __syncthreads();
  if (t < NHEAD) {
    float e2 = 0.f;
    for (int w2 = 0; w2 < 8; w2++) e2 += esums[w2][t];
    expsum_part[(b) * NHEAD + t] = e2;
  } else if (t == NHEAD) {
    float a = 0.f, q = 0.f;
    for (int w2 = 0; w2 < 8; w2++) { a += sstat[w2][0]; q += sstat[w2][1]; }
    stat_part[b * 2 + 0] = a;
    stat_part[b * 2 + 1] = q;
  }
  ((float4*)(fbar_part + (size_t)b * (NHEAD * D_)))[t] = ((float4*)fbar)[t];
}

// ---------------- Kernel D: combine partials + Wv + out-proj + LN + norm_aff ----------------
__global__ __launch_bounds__(1024) void finish_kernel(
    const float* __restrict__ slots,
    const float* __restrict__ expsum_part, const float* __restrict__ stat_part,
    const float* __restrict__ aff2_g, const float* __restrict__ fbar_part,
    const float* __restrict__ ipw, const float* __restrict__ ipb,
    const float* __restrict__ wout, const float* __restrict__ bout,
    const float* __restrict__ lnw, const float* __restrict__ lnb,
    float* __restrict__ slots_new, float* __restrict__ norm_aff) {
  __shared__ float fbar[NHEAD][D_];
  __shared__ float srow[D_];
  __shared__ float outv[D_];
  __shared__ float pq[1024];
  __shared__ float redS[4], redQ[4];
  int s = blockIdx.x, t = threadIdx.x, wave = t >> 6, lane = t & 63;

  // LN stats for norm_aff (uniform loads)
  float st0 = stat_part[s * 4 + 0] + stat_part[s * 4 + 2];
  float st1 = stat_part[s * 4 + 1] + stat_part[s * 4 + 3];
  float mean_a = st0 * (1.0f / NSEL);
  float var_a = st1 * (1.0f / NSEL) - mean_a * mean_a;
  float rstd_a = rsqrtf(var_a + 1e-5f);
  if (t < NSEL) norm_aff[(size_t)t * NSLOT + s] = (aff2_g[s * NSEL + t] - mean_a) * rstd_a;

  if (t < 512) {
    int h = t >> 6;  // fbar layout [8][256]: 64 float4s per head
    float inv = 1.0f / (expsum_part[s * 16 + h] + expsum_part[s * 16 + 8 + h]);
    const float4 a = ((const float4*)(fbar_part + (size_t)s * 4096))[t];
    const float4 c = ((const float4*)(fbar_part + (size_t)s * 4096 + 2048))[t];
    float4 r;
    r.x = (a.x + c.x) * inv; r.y = (a.y + c.y) * inv;
    r.z = (a.z + c.z) * inv; r.w = (a.w + c.w) * inv;
    ((float4*)fbar)[t] = r;
  }
  if (t < 64) ((float4*)srow)[t] = ((const float4*)(slots + (size_t)s * D_))[t];
  __syncthreads();

  // out = Wv . fbar(h) + bv  (quarter-dots)
  {
    int o = t >> 2, part = t & 3, h = o >> 5;
    const float4* wv = (const float4*)(ipw + (size_t)(2 * D_ + o) * D_ + part * 64);
    float a = 0.f;
#pragma unroll
    for (int i = 0; i < 16; i++) {
      float4 w = wv[i];
      int d = part * 64 + i * 4;
      a += fbar[h][d] * w.x + fbar[h][d + 1] * w.y + fbar[h][d + 2] * w.z + fbar[h][d + 3] * w.w;
    }
    pq[t] = a;
  }
  __syncthreads();
  if (t < D_)
    outv[t] = pq[t * 4] + pq[t * 4 + 1] + pq[t * 4 + 2] + pq[t * 4 + 3] + ipb[2 * D_ + t];
  __syncthreads();

  // slots_new = LN(srow + Wout.outv + bout) * lnw + lnb
  {
    int o = t >> 2, part = t & 3;
    const float4* w4 = (const float4*)(wout + (size_t)o * D_ + part * 64);
    float a = 0.f;
#pragma unroll
    for (int i = 0; i < 16; i++) {
      float4 w = w4[i];
      int d = part * 64 + i * 4;
      a += outv[d] * w.x + outv[d + 1] * w.y + outv[d + 2] * w.z + outv[d + 3] * w.w;
    }
    pq[t] = a;
  }
  __syncthreads();
  float v = 0.f;
  if (t < D_) {
    v = srow[t] + pq[t * 4] + pq[t * 4 + 1] + pq[t * 4 + 2] + pq[t * 4 + 3] + bout[t];
    float ls = v, lq = v * v;
#pragma unroll
    for (int off = 32; off >= 1; off >>= 1) { ls += __shfl_xor(ls, off, 64); lq += __shfl_xor(lq, off, 64); }
    if (lane == 0) { redS[wave] = ls; redQ[wave] = lq; }
  }
  __syncthreads();
  if (t < D_) {
    float tots = redS[0] + redS[1] + redS[2] + redS[3];
    float totq = redQ[0] + redQ[1] + redQ[2] + redQ[3];
    float mean = tots * (1.0f / D_);
    float var = totq * (1.0f / D_) - mean * mean;
    float rstd = rsqrtf(var + 1e-5f);
    slots_new[s * D_ + t] = (v - mean) * rstd * lnw[t] + lnb[t];
  }
}

extern "C" void kernel_launch(void* const* d_in, const int* in_sizes, int n_in,
                              void* d_out, int out_size, void* d_ws, size_t ws_size,
                              hipStream_t stream) {
  const float* slots    = (const float*)d_in[0];
  const float* features = (const float*)d_in[1];
  const float* posenc   = (const float*)d_in[2];
  const float* curio    = (const float*)d_in[3];
  const int*   batch_idx= (const int*)d_in[4];
  const float* ipw      = (const float*)d_in[5];
  const float* ipb      = (const float*)d_in[6];
  const float* wout     = (const float*)d_in[7];
  const float* bout     = (const float*)d_in[8];
  const float* lnw      = (const float*)d_in[9];
  const float* lnb      = (const float*)d_in[10];

  char* ws = (char*)d_ws;
  size_t off = 0;
  int*   feat_sel    = (int*)(ws + off);   off += 256 * 768 * 4;        // 786432
  float* qk_g        = (float*)(ws + off); off += 256 * 8 * 256 * 4;    // 2097152
  float* qbk_g       = (float*)(ws + off); off += 256 * 8 * 4;          // 8192
  float* fbar_part   = (float*)(ws + off); off += 256 * 2 * 8 * 256 * 4;// 4194304
  float* expsum_part = (float*)(ws + off); off += 256 * 2 * 8 * 4;      // 16384
  float* stat_part   = (float*)(ws + off); off += 256 * 2 * 2 * 4;      // 4096
  float* aff2_g      = (float*)(ws + off); off += 256 * 768 * 4;        // 786432

  float* out_f = (float*)d_out;  // [0,65536) slots_new, [65536,262144) norm_aff

  topk_kernel<<<NSLOT, 1024, 0, stream>>>(curio, feat_sel);
  qproj_kernel<<<NSLOT, 256, 0, stream>>>(slots, ipw, ipb, qk_g, qbk_g);
  aff_pv_kernel<<<NSLOT * 2, 512, 0, stream>>>(features, posenc, batch_idx, feat_sel,
                                               qk_g, qbk_g, fbar_part, expsum_part,
                                               stat_part, aff2_g);
  finish_kernel<<<NSLOT, 1024, 0, stream>>>(slots, expsum_part, stat_part, aff2_g,
                                            fbar_part, ipw, ipb, wout, bout, lnw, lnb,
                                            out_f, out_f + 65536);
}

// Round 7
// 176.884 us; speedup vs baseline: 1.4421x; 1.0706x over previous
//
#include <hip/hip_runtime.h>
#include <math.h>

#define NSLOT 256
#define HWN   16384
#define D_    256
#define BB    4
#define NSEL  768
#define NPOS  512
#define NHEAD 8

// Reduce 8 per-lane values over all 64 lanes simultaneously.
// Returns: full 64-lane sum of p[h], where h = (lane>>3)&7 for this lane.
__device__ __forceinline__ float reduce8x64(const float p[8], int lane) {
  float v[4];
#pragma unroll
  for (int h = 0; h < 4; h++) {
    float keep = (lane & 32) ? p[h + 4] : p[h];
    float send = (lane & 32) ? p[h] : p[h + 4];
    v[h] = keep + __shfl_xor(send, 32, 64);
  }
  float w[2];
#pragma unroll
  for (int h = 0; h < 2; h++) {
    float keep = (lane & 16) ? v[h + 2] : v[h];
    float send = (lane & 16) ? v[h] : v[h + 2];
    w[h] = keep + __shfl_xor(send, 16, 64);
  }
  float r;
  {
    float keep = (lane & 8) ? w[1] : w[0];
    float send = (lane & 8) ? w[0] : w[1];
    r = keep + __shfl_xor(send, 8, 64);
  }
  r += __shfl_xor(r, 4, 64);
  r += __shfl_xor(r, 2, 64);
  r += __shfl_xor(r, 1, 64);
  return r;
}

// ---------------- Kernel A: per-slot top-768 stable select (1024 thr) ----------------
__global__ __launch_bounds__(1024) void topk_kernel(const float* __restrict__ curio,
                                                    int* __restrict__ feat_sel) {
  __shared__ unsigned int hist[4096];
  __shared__ unsigned int wsum[16];
  __shared__ unsigned long long skey[2048];
  __shared__ int sBstar;
  __shared__ unsigned int sCount;
  int s = blockIdx.x;
  int t = threadIdx.x;
  int wave = t >> 6, lane = t & 63;
  const float* row = curio + (size_t)s * HWN;

  for (int i = t; i < 4096; i += 1024) hist[i] = 0;
  if (t == 0) sCount = 0;
  __syncthreads();
  for (int j = t; j < HWN; j += 1024) {
    unsigned int bits = __float_as_uint(row[j]);   // values in [0,1): bits monotone
    atomicAdd(&hist[bits >> 18], 1u);
  }
  __syncthreads();
  unsigned int cs = hist[t * 4] + hist[t * 4 + 1] + hist[t * 4 + 2] + hist[t * 4 + 3];
  unsigned int v = cs;
#pragma unroll
  for (int off = 1; off < 64; off <<= 1) {
    unsigned int u = __shfl_down(v, off, 64);
    if (lane + off < 64) v += u;       // suffix over lanes >= lane (this wave)
  }
  if (lane == 0) wsum[wave] = v;
  __syncthreads();
  unsigned int above = 0;
  for (int w2 = wave + 1; w2 < 16; w2++) above += wsum[w2];
  unsigned int sufAfter = above + (v - cs);
  if (sufAfter < NSEL && sufAfter + cs >= NSEL) {
    unsigned int local = sufAfter;
    for (int b = t * 4 + 3; b >= t * 4; b--) {
      unsigned int c = hist[b];
      if (local + c >= NSEL) { sBstar = b; break; }
      local += c;
    }
  }
  __syncthreads();
  int bstar = sBstar;
  for (int j = t; j < HWN; j += 1024) {
    unsigned int bits = __float_as_uint(row[j]);
    if ((int)(bits >> 18) >= bstar) {
      unsigned int pos = atomicAdd(&sCount, 1u);
      if (pos < 2048)
        skey[pos] = ((unsigned long long)bits << 14) | (unsigned long long)(16383 - j);
    }
  }
  __syncthreads();
  unsigned int M = sCount;
  int SZ = (M <= 1024) ? 1024 : 2048;
  for (int i = t; i < SZ; i += 1024) if (i >= (int)M) skey[i] = 0ull;
  for (int k = 2; k <= SZ; k <<= 1) {
    for (int j2 = k >> 1; j2 > 0; j2 >>= 1) {
      __syncthreads();
      for (int i = t; i < SZ; i += 1024) {
        int l = i ^ j2;
        if (l > i) {
          unsigned long long a = skey[i], b = skey[l];
          bool dir = ((i & k) == 0);
          if ((a < b) == dir) { skey[i] = b; skey[l] = a; }
        }
      }
    }
  }
  __syncthreads();
  for (int r = t; r < NSEL; r += 1024)
    feat_sel[s * NSEL + r] = 16383 - (int)(skey[r] & 16383ull);
}

// ---------------- Kernel B: q projection + qk = Wk^T q (per slot, 256 thr) ----------------
__global__ __launch_bounds__(256) void qproj_kernel(const float* __restrict__ slots,
                                                    const float* __restrict__ ipw,
                                                    const float* __restrict__ ipb,
                                                    float* __restrict__ qk_g,
                                                    float* __restrict__ qbk_g) {
  __shared__ float srow[D_];
  __shared__ float qrow[D_];
  int s = blockIdx.x, t = threadIdx.x;
  srow[t] = slots[s * D_ + t];
  __syncthreads();
  {
    const float* wq = ipw + (size_t)t * D_;
    float acc = ipb[t];
    for (int d = 0; d < D_; d++) acc += srow[d] * wq[d];
    qrow[t] = acc * 0.17677669529663689f;  // 1/sqrt(32)
  }
  __syncthreads();
  for (int h = 0; h < NHEAD; h++) {
    const float* wkbase = ipw + (size_t)(D_ + h * 32) * D_ + t;
    float a = 0.f;
    for (int e = 0; e < 32; e++) a += qrow[h * 32 + e] * wkbase[(size_t)e * D_];
    qk_g[((size_t)s * NHEAD + h) * D_ + t] = a;
  }
  if (t < NHEAD) {
    float a = 0.f;
    for (int e = 0; e < 32; e++) a += qrow[t * 32 + e] * ipb[D_ + t * 32 + e];
    qbk_g[s * NHEAD + t] = a;
  }
}

// ---------------- Kernel C: aff + fused PV partials. grid = (slot, half), 512 thr ----------------
// Block (s, half) handles local rows r=0..383 (global n = half + 2r): r<256 pos, else neg.
// Wave w: pos rows [32w, 32w+32), neg rows 256+[16w, 16w+16), processed in PAIRS
// (2 rows/iter) to keep live registers ~<100 (R6 lesson: 4-row unroll spilled at VGPR=64).
__global__ __launch_bounds__(512, 2) void aff_pv_kernel(
    const float* __restrict__ features, const float* __restrict__ posenc,
    const int* __restrict__ batch_idx, const int* __restrict__ feat_sel,
    const float* __restrict__ qk_g, const float* __restrict__ qbk_g,
    float* __restrict__ fbar_part,    // [256][2][8][256]
    float* __restrict__ expsum_part,  // [256][2][8]
    float* __restrict__ stat_part,    // [256][2][2]
    float* __restrict__ aff2_g) {     // [256][768]
  __shared__ float qks[NHEAD][D_];    // 8 KB
  __shared__ float fbar[NHEAD][D_];   // 8 KB
  __shared__ float wtile[8][2][8];    // 0.5 KB
  __shared__ int   sfsel[384];
  __shared__ float esums[8][NHEAD];
  __shared__ float sstat[8][2];
  __shared__ float qbkmean_s;

  int b = blockIdx.x, s = b >> 1, half = b & 1;
  int t = threadIdx.x, w = t >> 6, lane = t & 63;
  int bi = batch_idx[s];

  for (int i = t; i < NHEAD * D_; i += 512) {
    ((float*)qks)[i] = qk_g[(size_t)s * (NHEAD * D_) + i];
    ((float*)fbar)[i] = 0.f;
  }
  if (t < 384) sfsel[t] = feat_sel[s * NSEL + half + 2 * t];
  if (t == 0) {
    float m = 0.f;
    for (int h = 0; h < NHEAD; h++) m += qbk_g[s * NHEAD + h];
    qbkmean_s = m * 0.125f;
  }
  __syncthreads();
  float qbkmean = qbkmean_s;

  float acc[NHEAD][4];
#pragma unroll
  for (int h = 0; h < NHEAD; h++)
#pragma unroll
    for (int c = 0; c < 4; c++) acc[h][c] = 0.f;
  float esum = 0.f;              // valid on lanes with (lane&7)==0; head = lane>>3
  float st_s = 0.f, st_q = 0.f;  // valid on lane 0

  // ---- pos rows: aff + PV, 2 rows per iteration
  for (int r0 = 0; r0 < 32; r0 += 2) {
    int rA = w * 32 + r0, rB = rA + 1;
    int idxA = sfsel[rA], idxB = sfsel[rB];
    size_t baseA = ((size_t)idxA * BB + bi) * D_ + (size_t)(lane * 4);
    size_t baseB = ((size_t)idxB * BB + bi) * D_ + (size_t)(lane * 4);
    const float4 fA = *(const float4*)(features + baseA);
    const float4 pA = *(const float4*)(posenc + baseA);
    const float4 fB = *(const float4*)(features + baseB);
    const float4 pB = *(const float4*)(posenc + baseB);
    float4 kA, kB;
    kA.x = fA.x + pA.x; kA.y = fA.y + pA.y; kA.z = fA.z + pA.z; kA.w = fA.w + pA.w;
    kB.x = fB.x + pB.x; kB.y = fB.y + pB.y; kB.z = fB.z + pB.z; kB.w = fB.w + pB.w;
    float ppA[NHEAD], ppB[NHEAD];
#pragma unroll
    for (int h = 0; h < NHEAD; h++) {
      const float4 qw = *(const float4*)&qks[h][lane * 4];
      ppA[h] = kA.x * qw.x + kA.y * qw.y + kA.z * qw.z + kA.w * qw.w;
      ppB[h] = kB.x * qw.x + kB.y * qw.y + kB.z * qw.z + kB.w * qw.w;
    }
    float rsA = reduce8x64(ppA, lane);
    float rsB = reduce8x64(ppB, lane);
    float eA = __expf(rsA);
    float eB = __expf(rsB);
    if ((lane & 7) == 0) {
      int h = lane >> 3;
      wtile[w][0][h] = eA;
      wtile[w][1][h] = eB;
      esum += eA + eB;
    }
    float tA = rsA, tB = rsB;
    tA += __shfl_xor(tA, 8, 64);  tB += __shfl_xor(tB, 8, 64);
    tA += __shfl_xor(tA, 16, 64); tB += __shfl_xor(tB, 16, 64);
    tA += __shfl_xor(tA, 32, 64); tB += __shfl_xor(tB, 32, 64);
    if (lane == 0) {
      float a2A = tA * 0.125f + qbkmean;
      float a2B = tB * 0.125f + qbkmean;
      aff2_g[s * NSEL + half + 2 * rA] = a2A;
      aff2_g[s * NSEL + half + 2 * rB] = a2B;
      st_s += a2A + a2B; st_q += a2A * a2A + a2B * a2B;
    }
    // PV: weights broadcast from wtile (same-wave LDS, no barrier needed)
    {
      const float4 w0 = *(const float4*)&wtile[w][0][0];
      const float4 w1 = *(const float4*)&wtile[w][0][4];
      acc[0][0] += w0.x * fA.x; acc[0][1] += w0.x * fA.y; acc[0][2] += w0.x * fA.z; acc[0][3] += w0.x * fA.w;
      acc[1][0] += w0.y * fA.x; acc[1][1] += w0.y * fA.y; acc[1][2] += w0.y * fA.z; acc[1][3] += w0.y * fA.w;
      acc[2][0] += w0.z * fA.x; acc[2][1] += w0.z * fA.y; acc[2][2] += w0.z * fA.z; acc[2][3] += w0.z * fA.w;
      acc[3][0] += w0.w * fA.x; acc[3][1] += w0.w * fA.y; acc[3][2] += w0.w * fA.z; acc[3][3] += w0.w * fA.w;
      acc[4][0] += w1.x * fA.x; acc[4][1] += w1.x * fA.y; acc[4][2] += w1.x * fA.z; acc[4][3] += w1.x * fA.w;
      acc[5][0] += w1.y * fA.x; acc[5][1] += w1.y * fA.y; acc[5][2] += w1.y * fA.z; acc[5][3] += w1.y * fA.w;
      acc[6][0] += w1.z * fA.x; acc[6][1] += w1.z * fA.y; acc[6][2] += w1.z * fA.z; acc[6][3] += w1.z * fA.w;
      acc[7][0] += w1.w * fA.x; acc[7][1] += w1.w * fA.y; acc[7][2] += w1.w * fA.z; acc[7][3] += w1.w * fA.w;
    }
    {
      const float4 w0 = *(const float4*)&wtile[w][1][0];
      const float4 w1 = *(const float4*)&wtile[w][1][4];
      acc[0][0] += w0.x * fB.x; acc[0][1] += w0.x * fB.y; acc[0][2] += w0.x * fB.z; acc[0][3] += w0.x * fB.w;
      acc[1][0] += w0.y * fB.x; acc[1][1] += w0.y * fB.y; acc[1][2] += w0.y * fB.z; acc[1][3] += w0.y * fB.w;
      acc[2][0] += w0.z * fB.x; acc[2][1] += w0.z * fB.y; acc[2][2] += w0.z * fB.z; acc[2][3] += w0.z * fB.w;
      acc[3][0] += w0.w * fB.x; acc[3][1] += w0.w * fB.y; acc[3][2] += w0.w * fB.z; acc[3][3] += w0.w * fB.w;
      acc[4][0] += w1.x * fB.x; acc[4][1] += w1.x * fB.y; acc[4][2] += w1.x * fB.z; acc[4][3] += w1.x * fB.w;
      acc[5][0] += w1.y * fB.x; acc[5][1] += w1.y * fB.y; acc[5][2] += w1.y * fB.z; acc[5][3] += w1.y * fB.w;
      acc[6][0] += w1.z * fB.x; acc[6][1] += w1.z * fB.y; acc[6][2] += w1.z * fB.z; acc[6][3] += w1.z * fB.w;
      acc[7][0] += w1.w * fB.x; acc[7][1] += w1.w * fB.y; acc[7][2] += w1.w * fB.z; acc[7][3] += w1.w * fB.w;
    }
  }

  // ---- neg rows: aff only, 2 rows per iteration
  for (int r0 = 0; r0 < 16; r0 += 2) {
    int rA = 256 + w * 16 + r0, rB = rA + 1;
    int idxA = sfsel[rA], idxB = sfsel[rB];
    size_t baseA = ((size_t)idxA * BB + bi) * D_ + (size_t)(lane * 4);
    size_t baseB = ((size_t)idxB * BB + bi) * D_ + (size_t)(lane * 4);
    const float4 fA = *(const float4*)(features + baseA);
    const float4 pA = *(const float4*)(posenc + baseA);
    const float4 fB = *(const float4*)(features + baseB);
    const float4 pB = *(const float4*)(posenc + baseB);
    float4 kA, kB;
    kA.x = fA.x + pA.x; kA.y = fA.y + pA.y; kA.z = fA.z + pA.z; kA.w = fA.w + pA.w;
    kB.x = fB.x + pB.x; kB.y = fB.y + pB.y; kB.z = fB.z + pB.z; kB.w = fB.w + pB.w;
    float ppA[NHEAD], ppB[NHEAD];
#pragma unroll
    for (int h = 0; h < NHEAD; h++) {
      const float4 qw = *(const float4*)&qks[h][lane * 4];
      ppA[h] = kA.x * qw.x + kA.y * qw.y + kA.z * qw.z + kA.w * qw.w;
      ppB[h] = kB.x * qw.x + kB.y * qw.y + kB.z * qw.z + kB.w * qw.w;
    }
    float rsA = reduce8x64(ppA, lane);
    float rsB = reduce8x64(ppB, lane);
    float tA = rsA, tB = rsB;
    tA += __shfl_xor(tA, 8, 64);  tB += __shfl_xor(tB, 8, 64);
    tA += __shfl_xor(tA, 16, 64); tB += __shfl_xor(tB, 16, 64);
    tA += __shfl_xor(tA, 32, 64); tB += __shfl_xor(tB, 32, 64);
    if (lane == 0) {
      float a2A = tA * 0.125f + qbkmean;
      float a2B = tB * 0.125f + qbkmean;
      aff2_g[s * NSEL + half + 2 * rA] = a2A;
      aff2_g[s * NSEL + half + 2 * rB] = a2B;
      st_s += a2A + a2B; st_q += a2A * a2A + a2B * a2B;
    }
  }

  // ---- combine partials
  if ((lane & 7) == 0) esums[w][lane >> 3] = esum;
  if (lane == 0) { sstat[w][0] = st_s; sstat[w][1] = st_q; }
#pragma unroll
  for (int hh = 0; hh < NHEAD; hh++) {
    int h = (hh + w) & 7;  // stagger
    atomicAdd(&fbar[h][lane * 4 + 0], acc[h][0]);
    atomicAdd(&fbar[h][lane * 4 + 1], acc[h][1]);
    atomicAdd(&fbar[h][lane * 4 + 2], acc[h][2]);
    atomicAdd(&fbar[h][lane * 4 + 3], acc[h][3]);
  }
  __syncthreads();
  if (t < NHEAD) {
    float e2 = 0.f;
    for (int w2 = 0; w2 < 8; w2++) e2 += esums[w2][t];
    expsum_part[b * NHEAD + t] = e2;
  } else if (t == NHEAD) {
    float a = 0.f, q = 0.f;
    for (int w2 = 0; w2 < 8; w2++) { a += sstat[w2][0]; q += sstat[w2][1]; }
    stat_part[b * 2 + 0] = a;
    stat_part[b * 2 + 1] = q;
  }
  ((float4*)(fbar_part + (size_t)b * (NHEAD * D_)))[t] = ((float4*)fbar)[t];
}

// ---------------- Kernel D: combine partials + Wv + out-proj + LN + norm_aff ----------------
__global__ __launch_bounds__(1024) void finish_kernel(
    const float* __restrict__ slots,
    const float* __restrict__ expsum_part, const float* __restrict__ stat_part,
    const float* __restrict__ aff2_g, const float* __restrict__ fbar_part,
    const float* __restrict__ ipw, const float* __restrict__ ipb,
    const float* __restrict__ wout, const float* __restrict__ bout,
    const float* __restrict__ lnw, const float* __restrict__ lnb,
    float* __restrict__ slots_new, float* __restrict__ norm_aff) {
  __shared__ float fbar[NHEAD][D_];
  __shared__ float srow[D_];
  __shared__ float outv[D_];
  __shared__ float pq[1024];
  __shared__ float redS[4], redQ[4];
  int s = blockIdx.x, t = threadIdx.x, wave = t >> 6, lane = t & 63;

  // LN stats for norm_aff (uniform loads)
  float st0 = stat_part[s * 4 + 0] + stat_part[s * 4 + 2];
  float st1 = stat_part[s * 4 + 1] + stat_part[s * 4 + 3];
  float mean_a = st0 * (1.0f / NSEL);
  float var_a = st1 * (1.0f / NSEL) - mean_a * mean_a;
  float rstd_a = rsqrtf(var_a + 1e-5f);
  if (t < NSEL) norm_aff[(size_t)t * NSLOT + s] = (aff2_g[s * NSEL + t] - mean_a) * rstd_a;

  if (t < 512) {
    int h = t >> 6;  // fbar layout [8][256]: 64 float4s per head
    float inv = 1.0f / (expsum_part[s * 16 + h] + expsum_part[s * 16 + 8 + h]);
    const float4 a = ((const float4*)(fbar_part + (size_t)s * 4096))[t];
    const float4 c = ((const float4*)(fbar_part + (size_t)s * 4096 + 2048))[t];
    float4 r;
    r.x = (a.x + c.x) * inv; r.y = (a.y + c.y) * inv;
    r.z = (a.z + c.z) * inv; r.w = (a.w + c.w) * inv;
    ((float4*)fbar)[t] = r;
  }
  if (t < 64) ((float4*)srow)[t] = ((const float4*)(slots + (size_t)s * D_))[t];
  __syncthreads();

  // out = Wv . fbar(h) + bv  (quarter-dots)
  {
    int o = t >> 2, part = t & 3, h = o >> 5;
    const float4* wv = (const float4*)(ipw + (size_t)(2 * D_ + o) * D_ + part * 64);
    float a = 0.f;
#pragma unroll
    for (int i = 0; i < 16; i++) {
      float4 w = wv[i];
      int d = part * 64 + i * 4;
      a += fbar[h][d] * w.x + fbar[h][d + 1] * w.y + fbar[h][d + 2] * w.z + fbar[h][d + 3] * w.w;
    }
    pq[t] = a;
  }
  __syncthreads();
  if (t < D_)
    outv[t] = pq[t * 4] + pq[t * 4 + 1] + pq[t * 4 + 2] + pq[t * 4 + 3] + ipb[2 * D_ + t];
  __syncthreads();

  // slots_new = LN(srow + Wout.outv + bout) * lnw + lnb
  {
    int o = t >> 2, part = t & 3;
    const float4* w4 = (const float4*)(wout + (size_t)o * D_ + part * 64);
    float a = 0.f;
#pragma unroll
    for (int i = 0; i < 16; i++) {
      float4 w = w4[i];
      int d = part * 64 + i * 4;
      a += outv[d] * w.x + outv[d + 1] * w.y + outv[d + 2] * w.z + outv[d + 3] * w.w;
    }
    pq[t] = a;
  }
  __syncthreads();
  float v = 0.f;
  if (t < D_) {
    v = srow[t] + pq[t * 4] + pq[t * 4 + 1] + pq[t * 4 + 2] + pq[t * 4 + 3] + bout[t];
    float ls = v, lq = v * v;
#pragma unroll
    for (int off = 32; off >= 1; off >>= 1) { ls += __shfl_xor(ls, off, 64); lq += __shfl_xor(lq, off, 64); }
    if (lane == 0) { redS[wave] = ls; redQ[wave] = lq; }
  }
  __syncthreads();
  if (t < D_) {
    float tots = redS[0] + redS[1] + redS[2] + redS[3];
    float totq = redQ[0] + redQ[1] + redQ[2] + redQ[3];
    float mean = tots * (1.0f / D_);
    float var = totq * (1.0f / D_) - mean * mean;
    float rstd = rsqrtf(var + 1e-5f);
    slots_new[s * D_ + t] = (v - mean) * rstd * lnw[t] + lnb[t];
  }
}

extern "C" void kernel_launch(void* const* d_in, const int* in_sizes, int n_in,
                              void* d_out, int out_size, void* d_ws, size_t ws_size,
                              hipStream_t stream) {
  const float* slots    = (const float*)d_in[0];
  const float* features = (const float*)d_in[1];
  const float* posenc   = (const float*)d_in[2];
  const float* curio    = (const float*)d_in[3];
  const int*   batch_idx= (const int*)d_in[4];
  const float* ipw      = (const float*)d_in[5];
  const float* ipb      = (const float*)d_in[6];
  const float* wout     = (const float*)d_in[7];
  const float* bout     = (const float*)d_in[8];
  const float* lnw      = (const float*)d_in[9];
  const float* lnb      = (const float*)d_in[10];

  char* ws = (char*)d_ws;
  size_t off = 0;
  int*   feat_sel    = (int*)(ws + off);   off += 256 * 768 * 4;        // 786432
  float* qk_g        = (float*)(ws + off); off += 256 * 8 * 256 * 4;    // 2097152
  float* qbk_g       = (float*)(ws + off); off += 256 * 8 * 4;          // 8192
  float* fbar_part   = (float*)(ws + off); off += 256 * 2 * 8 * 256 * 4;// 4194304
  float* expsum_part = (float*)(ws + off); off += 256 * 2 * 8 * 4;      // 16384
  float* stat_part   = (float*)(ws + off); off += 256 * 2 * 2 * 4;      // 4096
  float* aff2_g      = (float*)(ws + off); off += 256 * 768 * 4;        // 786432

  float* out_f = (float*)d_out;  // [0,65536) slots_new, [65536,262144) norm_aff

  topk_kernel<<<NSLOT, 1024, 0, stream>>>(curio, feat_sel);
  qproj_kernel<<<NSLOT, 256, 0, stream>>>(slots, ipw, ipb, qk_g, qbk_g);
  aff_pv_kernel<<<NSLOT * 2, 512, 0, stream>>>(features, posenc, batch_idx, feat_sel,
                                               qk_g, qbk_g, fbar_part, expsum_part,
                                               stat_part, aff2_g);
  finish_kernel<<<NSLOT, 1024, 0, stream>>>(slots, expsum_part, stat_part, aff2_g,
                                            fbar_part, ipw, ipb, wout, bout, lnw, lnb,
                                            out_f, out_f + 65536);
}